// Round 8
// baseline (39.067 us; speedup 1.0000x reference)
//
#include <hip/hip_runtime.h>
#include <hip/hip_fp16.h>

// Problem constants (match reference)
#define NRAYS 1048576
#define NV 32
#define ND 32
#define NF 6
#define NK 13  // 2F+1

typedef _Float16 h2 __attribute__((ext_vector_type(2)));
typedef float f4 __attribute__((ext_vector_type(4)));

__device__ __forceinline__ float fdot2acc(h2 a, h2 b, float c) {
#if __has_builtin(__builtin_amdgcn_fdot2)
    return __builtin_amdgcn_fdot2(a, b, c, false);
#else
    return c + (float)a.x * (float)b.x + (float)a.y * (float)b.y;
#endif
}

__device__ __forceinline__ h2 pack2(float a, float b) {
#if __has_builtin(__builtin_amdgcn_cvt_pkrtz)
    return __builtin_bit_cast(h2, __builtin_amdgcn_cvt_pkrtz(a, b));
#else
    h2 r; r.x = (_Float16)a; r.y = (_Float16)b; return r;
#endif
}

__device__ __forceinline__ float hwsin(float rev) {
#if __has_builtin(__builtin_amdgcn_sinf)
    return __builtin_amdgcn_sinf(rev);
#else
    return __sinf(6.28318530717958647692f * rev);
#endif
}
__device__ __forceinline__ float hwcos(float rev) {
#if __has_builtin(__builtin_amdgcn_cosf)
    return __builtin_amdgcn_cosf(rev);
#else
    return __cosf(6.28318530717958647692f * rev);
#endif
}

// ---------------------------------------------------------------------------
// Kernel A: pack f32 weights [V][D][K] into the f16 image in d_ws, with the
// d-quad chunks XOR-swizzled by (v&7) inside each 128B row (breaks residual
// same-bank collisions when a wave still spans 2-3 distinct vids).
// Image (dwords): idx = v*224 + i*32 + pos*4 + e; chunk at `pos` holds
// d-quad q = pos ^ (v&7); dword e -> d = 4q+e, halves (k=2i, 2i+1).
__global__ void pack_weights_kernel(const float* __restrict__ weights,
                                    unsigned* __restrict__ wpack)
{
    int j = blockIdx.x * 256 + threadIdx.x;  // 0 .. 7167 (dwords)
    if (j >= NV * 7 * 32) return;
    int v = j / 224;
    int r = j - v * 224;
    int i = r >> 5;          // k-pair 0..6
    int c = r & 31;          // dword within 128B row
    int pos = c >> 2;        // chunk position 0..7
    int e = c & 3;           // dword within chunk
    int q = pos ^ (v & 7);   // d-quad stored at this position
    int d = 4 * q + e;
    float w0 = weights[v * (ND * NK) + d * NK + 2 * i];
    float w1 = (2 * i + 1 < NK) ? weights[v * (ND * NK) + d * NK + 2 * i + 1] : 0.f;
    h2 p = pack2(w0, w1);
    wpack[j] = __builtin_bit_cast(unsigned, p);
}

// ---------------------------------------------------------------------------
// Main kernel. Per 256-ray chunk: counting-sort rays by vid in LDS, then
// process in sorted order so each wave's 8 ray-groups share ~1-3 vids ->
// ds_read_b128 weight reads become same-address broadcasts (conflict-free).
// 8 threads per ray in the process phase: thread q owns d = 4q..4q+3.
__global__ __launch_bounds__(256, 5) void VideoEmbedding_kernel(
    const float* __restrict__ times,
    const int* __restrict__ vids,
    const unsigned* __restrict__ wpack,
    float* __restrict__ out)
{
    __shared__ _Float16 wl[NV * 7 * ND * 2];  // 28672 B
    __shared__ int hist[NV];
    __shared__ float s_t[256];
    __shared__ int s_meta[256];               // vid<<8 | local idx

    const int tid = threadIdx.x;

    // Stage the pre-packed image: 7 x uint4 per thread, fully coalesced.
    // (first __syncthreads below covers this before any wl read)
    {
        const uint4* src = reinterpret_cast<const uint4*>(wpack);
        uint4* dst = reinterpret_cast<uint4*>(wl);
#pragma unroll
        for (int j = 0; j < 7; ++j)
            dst[tid + j * 256] = src[tid + j * 256];
    }

    const int q = tid & 7;
    const int g = tid >> 3;  // ray-group 0..31

    const int NCHUNK = NRAYS / 256;  // 4096 (exact)
    for (int chunk = blockIdx.x; chunk < NCHUNK; chunk += gridDim.x) {
        const int base = chunk * 256;
        const float t = times[base + tid];   // coalesced, 1 ray/thread
        const int vid = vids[base + tid];

        if (tid < NV) hist[tid] = 0;
        __syncthreads();
        atomicAdd(&hist[vid], 1);
        __syncthreads();
        if (tid < NV) {
            int c = hist[tid];
            int sum = c;
#pragma unroll
            for (int off = 1; off < NV; off <<= 1) {
                int n = __shfl_up(sum, off, NV);
                if (tid >= off) sum += n;
            }
            hist[tid] = sum - c;  // exclusive prefix = bucket cursor
        }
        __syncthreads();
        {
            int pos = atomicAdd(&hist[vid], 1);
            s_t[pos] = t;
            s_meta[pos] = (vid << 8) | tid;
        }
        __syncthreads();

#pragma unroll 2
        for (int p = 0; p < 8; ++p) {
            const int slot = p * 32 + g;
            const float ts = s_t[slot];      // 8 lanes same addr: broadcast
            const int meta = s_meta[slot];
            const int v = meta >> 8;
            const int lidx = meta & 255;

            // basis: seed with HW trans (revolutions: 0.5t), double-angle up
            float sv[NF], cv[NF];
            sv[0] = hwsin(0.5f * ts);
            cv[0] = hwcos(0.5f * ts);
#pragma unroll
            for (int j = 1; j < NF; ++j) {
                float sj = sv[j - 1], cj = cv[j - 1];
                sv[j] = 2.f * sj * cj;
                cv[j] = fmaf(-2.f * sj, sj, 1.f);
            }

            h2 bp[7];
            bp[0] = pack2(1.0f, sv[0]);
            bp[1] = pack2(sv[1], sv[2]);
            bp[2] = pack2(sv[3], sv[4]);
            bp[3] = pack2(sv[5], cv[0]);
            bp[4] = pack2(cv[1], cv[2]);
            bp[5] = pack2(cv[3], cv[4]);
            bp[6] = pack2(cv[5], 0.0f);  // pad half must be 0

            const unsigned posq = (unsigned)(q ^ (v & 7));
            const unsigned baddr = (unsigned)v * 448u + posq * 8u;  // half idx
            float a0 = 0.f, a1 = 0.f, a2 = 0.f, a3 = 0.f;
#pragma unroll
            for (int i = 0; i < 7; ++i) {
                uint4 w = *reinterpret_cast<const uint4*>(&wl[baddr + i * 64]);
                a0 = fdot2acc(__builtin_bit_cast(h2, w.x), bp[i], a0);
                a1 = fdot2acc(__builtin_bit_cast(h2, w.y), bp[i], a1);
                a2 = fdot2acc(__builtin_bit_cast(h2, w.z), bp[i], a2);
                a3 = fdot2acc(__builtin_bit_cast(h2, w.w), bp[i], a3);
            }

            f4 res;
            res.x = a0; res.y = a1; res.z = a2; res.w = a3;
            __builtin_nontemporal_store(res,
                reinterpret_cast<f4*>(out) + (size_t)(base + lidx) * 8 + q);
        }
        __syncthreads();  // all s_t/s_meta reads done before next chunk
    }
}

extern "C" void kernel_launch(void* const* d_in, const int* in_sizes, int n_in,
                              void* d_out, int out_size, void* d_ws, size_t ws_size,
                              hipStream_t stream) {
    const float* times = (const float*)d_in[0];
    const int* vids = (const int*)d_in[1];
    const float* weights = (const float*)d_in[2];
    float* out = (float*)d_out;
    unsigned* wpack = (unsigned*)d_ws;

    hipLaunchKernelGGL(pack_weights_kernel, dim3(28), dim3(256), 0, stream,
                       weights, wpack);
    // 1280 blocks = 5 blocks/CU (LDS 30848 B/block), chunk-stride loop.
    hipLaunchKernelGGL(VideoEmbedding_kernel, dim3(1280), dim3(256), 0, stream,
                       times, vids, wpack, out);
}